// Round 1
// baseline (726.309 us; speedup 1.0000x reference)
//
#include <hip/hip_runtime.h>
#include <hip/hip_bf16.h>
#include <cstdint>

#define N_NODES 100000
#define N_EDGES 1600000
#define F_IN 256
#define F_HID 128
#define F_OUT 64
#define NEG_SLOPE 0.2f

// ---------------------------------------------------------------- GEMM ----
// C[M x BN] = A[M x K] @ B[K x BN], BN = full output width (no N tiling).
// Block = 256 threads. Each thread computes TM x TN outputs.
template <int BM, int BN, int BK, int TM, int TN>
__global__ __launch_bounds__(256) void gemm_kernel(
    const float* __restrict__ A, const float* __restrict__ B,
    float* __restrict__ C, int M, int K) {
  constexpr int TX = BN / TN;          // threads along N
  static_assert((BM / TM) * TX == 256, "bad config");

  __shared__ float As[BK][BM + 4];     // transposed A tile: As[k][m]
  __shared__ float Bs[BK][BN];

  const int tid = threadIdx.x;
  const int tc = tid % TX;             // N-group
  const int tr = tid / TX;             // M-group
  const int m0 = tr * TM;
  const int c0 = tc * TN;
  const int gm0 = blockIdx.x * BM;

  float acc[TM][TN];
#pragma unroll
  for (int i = 0; i < TM; ++i)
#pragma unroll
    for (int j = 0; j < TN; ++j) acc[i][j] = 0.f;

  for (int kt = 0; kt < K; kt += BK) {
    // load A tile (transposed into LDS)
#pragma unroll
    for (int i = tid; i < BM * BK / 4; i += 256) {
      int m = i / (BK / 4);
      int k4 = (i % (BK / 4)) * 4;
      int gm = gm0 + m;
      float4 v = make_float4(0.f, 0.f, 0.f, 0.f);
      if (gm < M) v = *(const float4*)(A + (size_t)gm * K + kt + k4);
      As[k4 + 0][m] = v.x;
      As[k4 + 1][m] = v.y;
      As[k4 + 2][m] = v.z;
      As[k4 + 3][m] = v.w;
    }
    // load B tile
#pragma unroll
    for (int i = tid; i < BK * BN / 4; i += 256) {
      int k = i / (BN / 4);
      int c4 = (i % (BN / 4)) * 4;
      *(float4*)&Bs[k][c4] = *(const float4*)(B + (size_t)(kt + k) * BN + c4);
    }
    __syncthreads();

#pragma unroll
    for (int k = 0; k < BK; ++k) {
      float av[TM];
      float bv[TN];
#pragma unroll
      for (int i = 0; i < TM; i += 4)
        *(float4*)&av[i] = *(const float4*)&As[k][m0 + i];
#pragma unroll
      for (int j = 0; j < TN; j += 4)
        *(float4*)&bv[j] = *(const float4*)&Bs[k][c0 + j];
#pragma unroll
      for (int i = 0; i < TM; ++i)
#pragma unroll
        for (int j = 0; j < TN; ++j) acc[i][j] = fmaf(av[i], bv[j], acc[i][j]);
    }
    __syncthreads();
  }

#pragma unroll
  for (int i = 0; i < TM; ++i) {
    int gm = gm0 + m0 + i;
    if (gm < M) {
#pragma unroll
      for (int j = 0; j < TN; j += 4) {
        float4 v = make_float4(acc[i][j], acc[i][j + 1], acc[i][j + 2], acc[i][j + 3]);
        *(float4*)(C + (size_t)gm * BN + c0 + j) = v;
      }
    }
  }
}

// ------------------------------------------------------------- alphas ----
// as[n] = h[n,:] . a_src ; ad[n] = h[n,:] . a_dst. One wave per node.
template <int C>
__global__ __launch_bounds__(256) void alpha_kernel(
    const float* __restrict__ h, const float* __restrict__ a_src,
    const float* __restrict__ a_dst, float* __restrict__ as_,
    float* __restrict__ ad_, int M) {
  int wid = (int)((blockIdx.x * (size_t)blockDim.x + threadIdx.x) >> 6);
  int lane = threadIdx.x & 63;
  if (wid >= M) return;
  const float* hp = h + (size_t)wid * C;
  float s = 0.f, d = 0.f;
#pragma unroll
  for (int c = lane; c < C; c += 64) {
    float hv = hp[c];
    s += hv * a_src[c];
    d += hv * a_dst[c];
  }
#pragma unroll
  for (int off = 32; off; off >>= 1) {
    s += __shfl_xor(s, off);
    d += __shfl_xor(d, off);
  }
  if (lane == 0) {
    as_[wid] = s;
    ad_[wid] = d;
  }
}

// ------------------------------------------------------------ CSR build ----
__global__ void hist_kernel(const int* __restrict__ dst, int* __restrict__ counts) {
  int i = blockIdx.x * blockDim.x + threadIdx.x;
  if (i < N_EDGES)
    atomicAdd(&counts[dst[i]], 1);
  else if (i < N_EDGES + N_NODES)
    atomicAdd(&counts[i - N_EDGES], 1);  // self-loop
}

// scan over 100000 counts: 98 blocks x 1024 elems
__global__ void scan1_kernel(const int* __restrict__ counts, int* __restrict__ offs,
                             int* __restrict__ partials) {
  __shared__ int sh[256];
  int t = threadIdx.x;
  int base = blockIdx.x * 1024 + t * 4;
  int v[4];
  int s = 0;
#pragma unroll
  for (int j = 0; j < 4; ++j) {
    v[j] = (base + j < N_NODES) ? counts[base + j] : 0;
    s += v[j];
  }
  sh[t] = s;
  __syncthreads();
  for (int off = 1; off < 256; off <<= 1) {
    int x = (t >= off) ? sh[t - off] : 0;
    __syncthreads();
    sh[t] += x;
    __syncthreads();
  }
  int run = sh[t] - s;  // exclusive prefix within block
  if (t == 255) partials[blockIdx.x] = sh[255];
#pragma unroll
  for (int j = 0; j < 4; ++j) {
    if (base + j < N_NODES) offs[base + j] = run;
    run += v[j];
  }
}

__global__ void scan2_kernel(int* __restrict__ partials, int P) {
  __shared__ int sh[256];
  int t = threadIdx.x;
  int v = (t < P) ? partials[t] : 0;
  sh[t] = v;
  __syncthreads();
  for (int off = 1; off < 256; off <<= 1) {
    int x = (t >= off) ? sh[t - off] : 0;
    __syncthreads();
    sh[t] += x;
    __syncthreads();
  }
  if (t < P) partials[t] = sh[t] - v;  // exclusive
}

__global__ void scan3_kernel(int* __restrict__ offs, const int* __restrict__ partials) {
  int add = partials[blockIdx.x];
  int base = blockIdx.x * 1024 + threadIdx.x * 4;
#pragma unroll
  for (int j = 0; j < 4; ++j)
    if (base + j < N_NODES) offs[base + j] += add;
}

__global__ void scatter_kernel(const int* __restrict__ src, const int* __restrict__ dst,
                               const int* __restrict__ offs, int* __restrict__ cursor,
                               int* __restrict__ csr_src) {
  int i = blockIdx.x * blockDim.x + threadIdx.x;
  int s, d;
  if (i < N_EDGES) {
    s = src[i];
    d = dst[i];
  } else if (i < N_EDGES + N_NODES) {
    s = d = i - N_EDGES;
  } else {
    return;
  }
  int pos = offs[d] + atomicAdd(&cursor[d], 1);
  csr_src[pos] = s;
}

// ------------------------------------------------------- GAT aggregation ----
// One wave per destination node: softmax over incoming edges + weighted sum.
template <int C, bool RELU>
__global__ __launch_bounds__(256) void agg_kernel(
    const float* __restrict__ h, const float* __restrict__ as_,
    const float* __restrict__ ad_, const int* __restrict__ offs,
    const int* __restrict__ counts, const int* __restrict__ csr_src,
    const float* __restrict__ bias, float* __restrict__ out, int M) {
  int wid = (int)((blockIdx.x * (size_t)blockDim.x + threadIdx.x) >> 6);
  int lane = threadIdx.x & 63;
  if (wid >= M) return;
  const int n = wid;
  const int start = offs[n];
  const int cnt = counts[n];
  const float adn = ad_[n];

  // pass 1: max logit
  float m = -3.402823e38f;
  for (int j = lane; j < cnt; j += 64) {
    float e = as_[csr_src[start + j]] + adn;
    e = (e >= 0.f) ? e : NEG_SLOPE * e;
    m = fmaxf(m, e);
  }
#pragma unroll
  for (int off = 32; off; off >>= 1) m = fmaxf(m, __shfl_xor(m, off));

  // pass 2: denom
  float ssum = 0.f;
  for (int j = lane; j < cnt; j += 64) {
    float e = as_[csr_src[start + j]] + adn;
    e = (e >= 0.f) ? e : NEG_SLOPE * e;
    ssum += __expf(e - m);
  }
#pragma unroll
  for (int off = 32; off; off >>= 1) ssum += __shfl_xor(ssum, off);
  const float inv = 1.0f / ssum;

  // pass 3: weighted accumulate
  constexpr int PC = C / 64;  // floats per lane (2 for C=128, 1 for C=64)
  float acc[PC];
#pragma unroll
  for (int p = 0; p < PC; ++p) acc[p] = 0.f;

  for (int j0 = 0; j0 < cnt; j0 += 64) {
    int j = j0 + lane;
    int sj = 0;
    float pj = 0.f;
    if (j < cnt) {
      sj = csr_src[start + j];
      float e = as_[sj] + adn;
      e = (e >= 0.f) ? e : NEG_SLOPE * e;
      pj = __expf(e - m) * inv;
    }
    int c2 = min(64, cnt - j0);
    for (int jj = 0; jj < c2; ++jj) {
      float coef = __shfl(pj, jj);
      int srcn = __shfl(sj, jj);
      const float* hp = h + (size_t)srcn * C;
      if (PC == 2) {
        float2 v = ((const float2*)hp)[lane];
        acc[0] += coef * v.x;
        acc[1] += coef * v.y;
      } else {
        acc[0] += coef * hp[lane];
      }
    }
  }

  if (PC == 2) {
    float r0 = acc[0] + bias[2 * lane];
    float r1 = acc[1] + bias[2 * lane + 1];
    if (RELU) {
      r0 = fmaxf(r0, 0.f);
      r1 = fmaxf(r1, 0.f);
    }
    float2* op = (float2*)(out + (size_t)n * C);
    op[lane] = make_float2(r0, r1);
  } else {
    float r0 = acc[0] + bias[lane];
    if (RELU) r0 = fmaxf(r0, 0.f);
    out[(size_t)n * C + lane] = r0;
  }
}

// ---------------------------------------------------------------- launch ----
extern "C" void kernel_launch(void* const* d_in, const int* in_sizes, int n_in,
                              void* d_out, int out_size, void* d_ws, size_t ws_size,
                              hipStream_t stream) {
  const float* x = (const float*)d_in[0];
  const int* ei = (const int*)d_in[1];
  const float* W1 = (const float*)d_in[2];
  const float* a1s = (const float*)d_in[3];
  const float* a1d = (const float*)d_in[4];
  const float* b1 = (const float*)d_in[5];
  const float* W2 = (const float*)d_in[6];
  const float* a2s = (const float*)d_in[7];
  const float* a2d = (const float*)d_in[8];
  const float* b2 = (const float*)d_in[9];
  float* out = (float*)d_out;

  const int* esrc = ei;
  const int* edst = ei + N_EDGES;

  // workspace layout
  char* ws = (char*)d_ws;
  size_t off = 0;
  auto alloc = [&](size_t bytes) {
    size_t o = off;
    off = (off + bytes + 255) & ~(size_t)255;
    return o;
  };
  float* h1 = (float*)(ws + alloc((size_t)N_NODES * F_HID * 4));
  float* hrelu = (float*)(ws + alloc((size_t)N_NODES * F_HID * 4));
  float* h2 = (float*)(ws + alloc((size_t)N_NODES * F_OUT * 4));
  float* as1 = (float*)(ws + alloc((size_t)N_NODES * 4));
  float* ad1 = (float*)(ws + alloc((size_t)N_NODES * 4));
  float* as2 = (float*)(ws + alloc((size_t)N_NODES * 4));
  float* ad2 = (float*)(ws + alloc((size_t)N_NODES * 4));
  int* counts = (int*)(ws + alloc((size_t)N_NODES * 4));
  int* offs = (int*)(ws + alloc((size_t)N_NODES * 4));
  int* cursor = (int*)(ws + alloc((size_t)N_NODES * 4));
  int* csr_src = (int*)(ws + alloc((size_t)(N_EDGES + N_NODES) * 4));
  int* partials = (int*)(ws + alloc(1024 * 4));

  const int TOT = N_EDGES + N_NODES;
  const int SCAN_BLKS = (N_NODES + 1023) / 1024;  // 98

  hipMemsetAsync(counts, 0, (size_t)N_NODES * 4, stream);
  hipMemsetAsync(cursor, 0, (size_t)N_NODES * 4, stream);

  // CSR build
  hist_kernel<<<(TOT + 255) / 256, 256, 0, stream>>>(edst, counts);
  scan1_kernel<<<SCAN_BLKS, 256, 0, stream>>>(counts, offs, partials);
  scan2_kernel<<<1, 256, 0, stream>>>(partials, SCAN_BLKS);
  scan3_kernel<<<SCAN_BLKS, 256, 0, stream>>>(offs, partials);
  scatter_kernel<<<(TOT + 255) / 256, 256, 0, stream>>>(esrc, edst, offs, cursor, csr_src);

  // layer 1
  gemm_kernel<64, 128, 32, 8, 4>
      <<<(N_NODES + 63) / 64, 256, 0, stream>>>(x, W1, h1, N_NODES, F_IN);
  alpha_kernel<F_HID>
      <<<(N_NODES + 3) / 4, 256, 0, stream>>>(h1, a1s, a1d, as1, ad1, N_NODES);
  agg_kernel<F_HID, true><<<(N_NODES + 3) / 4, 256, 0, stream>>>(
      h1, as1, ad1, offs, counts, csr_src, b1, hrelu, N_NODES);

  // layer 2
  gemm_kernel<128, 64, 32, 8, 4>
      <<<(N_NODES + 127) / 128, 256, 0, stream>>>(hrelu, W2, h2, N_NODES, F_HID);
  alpha_kernel<F_OUT>
      <<<(N_NODES + 3) / 4, 256, 0, stream>>>(h2, a2s, a2d, as2, ad2, N_NODES);
  agg_kernel<F_OUT, false><<<(N_NODES + 3) / 4, 256, 0, stream>>>(
      h2, as2, ad2, offs, counts, csr_src, b2, out, N_NODES);
}

// Round 2
// 543.500 us; speedup vs baseline: 1.3364x; 1.3364x over previous
//
#include <hip/hip_runtime.h>
#include <hip/hip_bf16.h>
#include <cstdint>

#define N_NODES 100000
#define N_EDGES 1600000
#define F_IN 256
#define F_HID 128
#define F_OUT 64
#define NEG_SLOPE 0.2f

typedef __attribute__((ext_vector_type(8))) short bf16x8;
typedef __attribute__((ext_vector_type(4))) float f32x4;

__device__ __forceinline__ ushort f2bf(float f) {
  uint u = __float_as_uint(f);
  u += 0x7fffu + ((u >> 16) & 1u);   // RNE
  return (ushort)(u >> 16);
}
__device__ __forceinline__ float bf2f(ushort s) {
  return __uint_as_float(((uint)s) << 16);
}
__device__ __forceinline__ uint pack2(float a, float b) {
  return (uint)f2bf(a) | ((uint)f2bf(b) << 16);
}

// ------------------------------------------------- W prep: transpose + bf16
__global__ void wprep_kernel(const float* __restrict__ W, ushort* __restrict__ Wt,
                             int K, int Ncol) {
  int i = blockIdx.x * blockDim.x + threadIdx.x;
  if (i < K * Ncol) {
    int k = i / Ncol, c = i % Ncol;
    Wt[(size_t)c * K + k] = f2bf(W[i]);
  }
}

// ----------------------------------------------------------- MFMA GEMM ----
// C[M x BN] (bf16) = A[M x K] @ Bt^T, Bt is [BN][K] bf16. Block: 256 thr,
// BM=128, 4 waves each own 32 rows x BN cols. K-step 32, 16x16x32 mfma.
template <int BN, int K, bool AF32>
__global__ __launch_bounds__(256) void gemm_mfma(
    const void* __restrict__ Ap, const ushort* __restrict__ Bt,
    ushort* __restrict__ Cb, int M) {
  constexpr int CT = BN / 16;
  __shared__ __align__(16) ushort Alds[128 * 32];
  __shared__ __align__(16) ushort Blds[BN * 32];
  const int tid = threadIdx.x;
  const int wave = tid >> 6, lane = tid & 63;
  const int lr = lane & 15, lq = lane >> 4;
  const int gm0 = blockIdx.x * 128;

  f32x4 acc[2][CT];
#pragma unroll
  for (int a = 0; a < 2; ++a)
#pragma unroll
    for (int b = 0; b < CT; ++b)
#pragma unroll
      for (int e = 0; e < 4; ++e) acc[a][b][e] = 0.f;

  for (int kt = 0; kt < K; kt += 32) {
    // A stage: 512 segs of 16B (8 bf16), seg-XOR swizzled
#pragma unroll
    for (int i = 0; i < 2; ++i) {
      int sid = i * 256 + tid;
      int row = sid >> 2, q = sid & 3;
      int gm = gm0 + row;
      uint4 w = make_uint4(0u, 0u, 0u, 0u);
      if (gm < M) {
        if (AF32) {
          const float* s = (const float*)Ap + (size_t)gm * K + kt + q * 8;
          float4 u = *(const float4*)s;
          float4 v = *(const float4*)(s + 4);
          w.x = pack2(u.x, u.y); w.y = pack2(u.z, u.w);
          w.z = pack2(v.x, v.y); w.w = pack2(v.z, v.w);
        } else {
          w = *(const uint4*)((const ushort*)Ap + (size_t)gm * K + kt + q * 8);
        }
      }
      int phys = row * 4 + (q ^ ((row >> 2) & 3));
      *(uint4*)&Alds[phys * 8] = w;
    }
    // B stage
#pragma unroll
    for (int i = 0; i < BN * 4 / 256; ++i) {
      int sid = i * 256 + tid;
      int row = sid >> 2, q = sid & 3;
      uint4 w = *(const uint4*)(Bt + (size_t)row * K + kt + q * 8);
      int phys = row * 4 + (q ^ ((row >> 2) & 3));
      *(uint4*)&Blds[phys * 8] = w;
    }
    __syncthreads();

    bf16x8 af[2], bfr[CT];
#pragma unroll
    for (int rt = 0; rt < 2; ++rt) {
      int r = wave * 32 + rt * 16 + lr;
      af[rt] = *(const bf16x8*)&Alds[(r * 4 + (lq ^ ((r >> 2) & 3))) * 8];
    }
#pragma unroll
    for (int c = 0; c < CT; ++c) {
      int r = c * 16 + lr;
      bfr[c] = *(const bf16x8*)&Blds[(r * 4 + (lq ^ ((r >> 2) & 3))) * 8];
    }
#pragma unroll
    for (int rt = 0; rt < 2; ++rt)
#pragma unroll
      for (int c = 0; c < CT; ++c)
        acc[rt][c] = __builtin_amdgcn_mfma_f32_16x16x32_bf16(af[rt], bfr[c], acc[rt][c], 0, 0, 0);
    __syncthreads();
  }

  // epilogue: C/D layout col=lane&15, row=(lane>>4)*4+reg
#pragma unroll
  for (int rt = 0; rt < 2; ++rt)
#pragma unroll
    for (int ri = 0; ri < 4; ++ri) {
      int gr = gm0 + wave * 32 + rt * 16 + lq * 4 + ri;
      if (gr < M) {
#pragma unroll
        for (int c = 0; c < CT; ++c)
          Cb[(size_t)gr * BN + c * 16 + lr] = f2bf(acc[rt][c][ri]);
      }
    }
}

// ------------------------------------------------------------- alphas ----
template <int C>
__global__ __launch_bounds__(256) void alpha_kernel(
    const ushort* __restrict__ h, const float* __restrict__ a_src,
    const float* __restrict__ a_dst, float* __restrict__ as_,
    float* __restrict__ ad_, int M) {
  int wid = (int)((blockIdx.x * (size_t)blockDim.x + threadIdx.x) >> 6);
  int lane = threadIdx.x & 63;
  if (wid >= M) return;
  const ushort* hp = h + (size_t)wid * C;
  float s, d;
  if (C == 128) {
    uint v = ((const uint*)hp)[lane];
    float h0 = bf2f((ushort)(v & 0xffffu)), h1 = bf2f((ushort)(v >> 16));
    s = h0 * a_src[2 * lane] + h1 * a_src[2 * lane + 1];
    d = h0 * a_dst[2 * lane] + h1 * a_dst[2 * lane + 1];
  } else {
    float h0 = bf2f(hp[lane]);
    s = h0 * a_src[lane];
    d = h0 * a_dst[lane];
  }
#pragma unroll
  for (int off = 32; off; off >>= 1) {
    s += __shfl_xor(s, off);
    d += __shfl_xor(d, off);
  }
  if (lane == 0) {
    as_[wid] = s;
    ad_[wid] = d;
  }
}

// ------------------------------------------------------------ CSR build ----
__global__ void hist_kernel(const int* __restrict__ dst, int* __restrict__ counts) {
  int i = blockIdx.x * blockDim.x + threadIdx.x;
  if (i < N_EDGES)
    atomicAdd(&counts[dst[i]], 1);
  else if (i < N_EDGES + N_NODES)
    atomicAdd(&counts[i - N_EDGES], 1);
}

__global__ void scan1_kernel(const int* __restrict__ counts, int* __restrict__ offs,
                             int* __restrict__ partials) {
  __shared__ int sh[256];
  int t = threadIdx.x;
  int base = blockIdx.x * 1024 + t * 4;
  int v[4];
  int s = 0;
#pragma unroll
  for (int j = 0; j < 4; ++j) {
    v[j] = (base + j < N_NODES) ? counts[base + j] : 0;
    s += v[j];
  }
  sh[t] = s;
  __syncthreads();
  for (int off = 1; off < 256; off <<= 1) {
    int x = (t >= off) ? sh[t - off] : 0;
    __syncthreads();
    sh[t] += x;
    __syncthreads();
  }
  int run = sh[t] - s;
  if (t == 255) partials[blockIdx.x] = sh[255];
#pragma unroll
  for (int j = 0; j < 4; ++j) {
    if (base + j < N_NODES) offs[base + j] = run;
    run += v[j];
  }
}

__global__ void scan2_kernel(int* __restrict__ partials, int P) {
  __shared__ int sh[256];
  int t = threadIdx.x;
  int v = (t < P) ? partials[t] : 0;
  sh[t] = v;
  __syncthreads();
  for (int off = 1; off < 256; off <<= 1) {
    int x = (t >= off) ? sh[t - off] : 0;
    __syncthreads();
    sh[t] += x;
    __syncthreads();
  }
  if (t < P) partials[t] = sh[t] - v;
}

__global__ void scan3_kernel(int* __restrict__ offs, const int* __restrict__ partials) {
  int add = partials[blockIdx.x];
  int base = blockIdx.x * 1024 + threadIdx.x * 4;
#pragma unroll
  for (int j = 0; j < 4; ++j)
    if (base + j < N_NODES) offs[base + j] += add;
}

__global__ void scatter_kernel(const int* __restrict__ src, const int* __restrict__ dst,
                               const int* __restrict__ offs, int* __restrict__ cursor,
                               int* __restrict__ csr_src) {
  int i = blockIdx.x * blockDim.x + threadIdx.x;
  int s, d;
  if (i < N_EDGES) {
    s = src[i];
    d = dst[i];
  } else if (i < N_EDGES + N_NODES) {
    s = d = i - N_EDGES;
  } else {
    return;
  }
  int pos = offs[d] + atomicAdd(&cursor[d], 1);
  csr_src[pos] = s;
}

// ------------------------------------------------------- GAT aggregation ----
// One wave per destination node; h is bf16 [M][C]. Online softmax (1 pass)
// then gather pass with x4 unroll for MLP.
template <int C, bool RELU, bool OUTBF>
__global__ __launch_bounds__(256) void agg_kernel(
    const ushort* __restrict__ h, const float* __restrict__ as_,
    const float* __restrict__ ad_, const int* __restrict__ offs,
    const int* __restrict__ counts, const int* __restrict__ csr_src,
    const float* __restrict__ bias, void* __restrict__ outp, int M) {
  int wid = (int)((blockIdx.x * (size_t)blockDim.x + threadIdx.x) >> 6);
  int lane = threadIdx.x & 63;
  if (wid >= M) return;
  const int start = offs[wid];
  const int cnt = counts[wid];
  const float adn = ad_[wid];

  // online max + denom
  float m = -3.402823e38f, ssum = 0.f;
  for (int j = lane; j < cnt; j += 64) {
    float e = as_[csr_src[start + j]] + adn;
    e = (e >= 0.f) ? e : NEG_SLOPE * e;
    float mn = fmaxf(m, e);
    ssum = ssum * __expf(m - mn) + __expf(e - mn);
    m = mn;
  }
#pragma unroll
  for (int off = 32; off; off >>= 1) {
    float mo = __shfl_xor(m, off), so = __shfl_xor(ssum, off);
    float mn = fmaxf(m, mo);
    ssum = ssum * __expf(m - mn) + so * __expf(mo - mn);
    m = mn;
  }
  const float inv = 1.0f / ssum;

  float acc0 = 0.f, acc1 = 0.f;
  for (int j0 = 0; j0 < cnt; j0 += 64) {
    int j = j0 + lane;
    int sj = 0;
    float pj = 0.f;
    if (j < cnt) {
      sj = csr_src[start + j];
      float e = as_[sj] + adn;
      e = (e >= 0.f) ? e : NEG_SLOPE * e;
      pj = __expf(e - m) * inv;
    }
    int c2 = min(64, cnt - j0);
    int jj = 0;
    for (; jj + 4 <= c2; jj += 4) {
      int s0 = __shfl(sj, jj), s1 = __shfl(sj, jj + 1);
      int s2 = __shfl(sj, jj + 2), s3 = __shfl(sj, jj + 3);
      float p0 = __shfl(pj, jj), p1 = __shfl(pj, jj + 1);
      float p2 = __shfl(pj, jj + 2), p3 = __shfl(pj, jj + 3);
      if (C == 128) {
        uint v0 = ((const uint*)(h + (size_t)s0 * C))[lane];
        uint v1 = ((const uint*)(h + (size_t)s1 * C))[lane];
        uint v2 = ((const uint*)(h + (size_t)s2 * C))[lane];
        uint v3 = ((const uint*)(h + (size_t)s3 * C))[lane];
        acc0 += p0 * bf2f((ushort)(v0 & 0xffffu));
        acc1 += p0 * bf2f((ushort)(v0 >> 16));
        acc0 += p1 * bf2f((ushort)(v1 & 0xffffu));
        acc1 += p1 * bf2f((ushort)(v1 >> 16));
        acc0 += p2 * bf2f((ushort)(v2 & 0xffffu));
        acc1 += p2 * bf2f((ushort)(v2 >> 16));
        acc0 += p3 * bf2f((ushort)(v3 & 0xffffu));
        acc1 += p3 * bf2f((ushort)(v3 >> 16));
      } else {
        float v0 = bf2f(h[(size_t)s0 * C + lane]);
        float v1 = bf2f(h[(size_t)s1 * C + lane]);
        float v2 = bf2f(h[(size_t)s2 * C + lane]);
        float v3 = bf2f(h[(size_t)s3 * C + lane]);
        acc0 += p0 * v0 + p1 * v1 + p2 * v2 + p3 * v3;
      }
    }
    for (; jj < c2; ++jj) {
      int s0 = __shfl(sj, jj);
      float p0 = __shfl(pj, jj);
      if (C == 128) {
        uint v0 = ((const uint*)(h + (size_t)s0 * C))[lane];
        acc0 += p0 * bf2f((ushort)(v0 & 0xffffu));
        acc1 += p0 * bf2f((ushort)(v0 >> 16));
      } else {
        acc0 += p0 * bf2f(h[(size_t)s0 * C + lane]);
      }
    }
  }

  if (C == 128) {
    float r0 = acc0 + bias[2 * lane];
    float r1 = acc1 + bias[2 * lane + 1];
    if (RELU) {
      r0 = fmaxf(r0, 0.f);
      r1 = fmaxf(r1, 0.f);
    }
    if (OUTBF)
      ((uint*)outp)[(size_t)wid * (C / 2) + lane] = pack2(r0, r1);
    else
      ((float2*)outp)[(size_t)wid * (C / 2) + lane] = make_float2(r0, r1);
  } else {
    float r0 = acc0 + bias[lane];
    if (RELU) r0 = fmaxf(r0, 0.f);
    if (OUTBF)
      ((ushort*)outp)[(size_t)wid * C + lane] = f2bf(r0);
    else
      ((float*)outp)[(size_t)wid * C + lane] = r0;
  }
}

// ---------------------------------------------------------------- launch ----
extern "C" void kernel_launch(void* const* d_in, const int* in_sizes, int n_in,
                              void* d_out, int out_size, void* d_ws, size_t ws_size,
                              hipStream_t stream) {
  const float* x = (const float*)d_in[0];
  const int* ei = (const int*)d_in[1];
  const float* W1 = (const float*)d_in[2];
  const float* a1s = (const float*)d_in[3];
  const float* a1d = (const float*)d_in[4];
  const float* b1 = (const float*)d_in[5];
  const float* W2 = (const float*)d_in[6];
  const float* a2s = (const float*)d_in[7];
  const float* a2d = (const float*)d_in[8];
  const float* b2 = (const float*)d_in[9];
  float* out = (float*)d_out;

  const int* esrc = ei;
  const int* edst = ei + N_EDGES;

  char* ws = (char*)d_ws;
  size_t off = 0;
  auto alloc = [&](size_t bytes) {
    size_t o = off;
    off = (off + bytes + 255) & ~(size_t)255;
    return o;
  };
  ushort* h1b = (ushort*)(ws + alloc((size_t)N_NODES * F_HID * 2));
  ushort* hrb = (ushort*)(ws + alloc((size_t)N_NODES * F_HID * 2));
  ushort* h2b = (ushort*)(ws + alloc((size_t)N_NODES * F_OUT * 2));
  float* as1 = (float*)(ws + alloc((size_t)N_NODES * 4));
  float* ad1 = (float*)(ws + alloc((size_t)N_NODES * 4));
  float* as2 = (float*)(ws + alloc((size_t)N_NODES * 4));
  float* ad2 = (float*)(ws + alloc((size_t)N_NODES * 4));
  int* counts = (int*)(ws + alloc((size_t)N_NODES * 4));
  int* offs = (int*)(ws + alloc((size_t)N_NODES * 4));
  int* cursor = (int*)(ws + alloc((size_t)N_NODES * 4));
  int* csr_src = (int*)(ws + alloc((size_t)(N_EDGES + N_NODES) * 4));
  int* partials = (int*)(ws + alloc(1024 * 4));
  ushort* W1t = (ushort*)(ws + alloc((size_t)F_IN * F_HID * 2));
  ushort* W2t = (ushort*)(ws + alloc((size_t)F_HID * F_OUT * 2));

  const int TOT = N_EDGES + N_NODES;
  const int SCAN_BLKS = (N_NODES + 1023) / 1024;

  hipMemsetAsync(counts, 0, (size_t)N_NODES * 4, stream);
  hipMemsetAsync(cursor, 0, (size_t)N_NODES * 4, stream);

  // CSR build
  hist_kernel<<<(TOT + 255) / 256, 256, 0, stream>>>(edst, counts);
  scan1_kernel<<<SCAN_BLKS, 256, 0, stream>>>(counts, offs, partials);
  scan2_kernel<<<1, 256, 0, stream>>>(partials, SCAN_BLKS);
  scan3_kernel<<<SCAN_BLKS, 256, 0, stream>>>(offs, partials);
  scatter_kernel<<<(TOT + 255) / 256, 256, 0, stream>>>(esrc, edst, offs, cursor, csr_src);

  // weight prep
  wprep_kernel<<<(F_IN * F_HID + 255) / 256, 256, 0, stream>>>(W1, W1t, F_IN, F_HID);
  wprep_kernel<<<(F_HID * F_OUT + 255) / 256, 256, 0, stream>>>(W2, W2t, F_HID, F_OUT);

  // layer 1
  gemm_mfma<F_HID, F_IN, true>
      <<<(N_NODES + 127) / 128, 256, 0, stream>>>(x, W1t, h1b, N_NODES);
  alpha_kernel<F_HID>
      <<<(N_NODES + 3) / 4, 256, 0, stream>>>(h1b, a1s, a1d, as1, ad1, N_NODES);
  agg_kernel<F_HID, true, true><<<(N_NODES + 3) / 4, 256, 0, stream>>>(
      h1b, as1, ad1, offs, counts, csr_src, b1, hrb, N_NODES);

  // layer 2
  gemm_mfma<F_OUT, F_HID, false>
      <<<(N_NODES + 127) / 128, 256, 0, stream>>>(hrb, W2t, h2b, N_NODES);
  alpha_kernel<F_OUT>
      <<<(N_NODES + 3) / 4, 256, 0, stream>>>(h2b, a2s, a2d, as2, ad2, N_NODES);
  agg_kernel<F_OUT, false, false><<<(N_NODES + 3) / 4, 256, 0, stream>>>(
      h2b, as2, ad2, offs, counts, csr_src, b2, out, N_NODES);
}